// Round 4
// baseline (56.285 us; speedup 1.0000x reference)
//
#include <hip/hip_runtime.h>
#include <hip/hip_bf16.h>
#include <math.h>

#define N_HALF 2048
#define M_TOT  4096
#define D_DIM  256
#define K2     512
#define NBLK   32            // M_TOT / 128 column blocks
#define KB     16            // K2 / 32 k-steps
#define TILE_BYTES 8192      // 128 rows * 32 k * 2 B

typedef __attribute__((ext_vector_type(8))) short bf16x8;
typedef __attribute__((ext_vector_type(4))) float f32x4;

static __device__ __forceinline__ unsigned short f2bf(float x) {
    union { __hip_bfloat16 h; unsigned short u; } cv;
    cv.h = __float2bfloat16(x);
    return cv.u;
}

static __device__ __forceinline__ void gll16(const void* g, void* l) {
    __builtin_amdgcn_global_load_lds(
        (const __attribute__((address_space(1))) unsigned int*)g,
        (__attribute__((address_space(3))) unsigned int*)l, 16, 0, 0);
}

// ---------------------------------------------------------------------------
// Kernel 1: build bf16 GEMM operands (pre-swizzled, tile-major) + row scalars.
//   A[i] = [mu^2+var , -2*mu],  B[j] = [1/var , mu/var]   (each K=512)
//   Tile layout: (rowblk, kblk) tiles of 128x32 bf16 (8192 B), 16B-slot
//   XOR-swizzled: slot' = slot ^ ((r>>1)&3), so a linear global_load_lds
//   yields the swizzled LDS image directly.
//   One wave per row: float4 loads, shuffle reductions, single __logf of the
//   4-way product (vars in [0.5,1.5) -> product in [0.06,5.1], safe).
// ---------------------------------------------------------------------------
__global__ __launch_bounds__(256) void prep_kernel(
        const float* __restrict__ loc1, const float* __restrict__ scale1,
        const float* __restrict__ loc2, const float* __restrict__ scale2,
        unsigned short* __restrict__ Ab, unsigned short* __restrict__ Bb,
        float* __restrict__ slv, float* __restrict__ cvec) {
    const int t = threadIdx.x, w = t >> 6, lane = t & 63;
    const int i = blockIdx.x * 4 + w;
    const float* mup  = (i < N_HALF) ? loc1 + (size_t)i * D_DIM   : loc2 + (size_t)(i - N_HALF) * D_DIM;
    const float* vap  = (i < N_HALF) ? scale1 + (size_t)i * D_DIM : scale2 + (size_t)(i - N_HALF) * D_DIM;
    const float4 mu = *(const float4*)(mup + lane * 4);
    const float4 va = *(const float4*)(vap + lane * 4);
    const float4 iv = {1.0f / va.x, 1.0f / va.y, 1.0f / va.z, 1.0f / va.w};

    float lacc = __logf(va.x * va.y * va.z * va.w);
    float cacc = mu.x * mu.x * iv.x + mu.y * mu.y * iv.y
               + mu.z * mu.z * iv.z + mu.w * mu.w * iv.w;
    #pragma unroll
    for (int off = 1; off < 64; off <<= 1) {
        lacc += __shfl_xor(lacc, off, 64);
        cacc += __shfl_xor(cacc, off, 64);
    }
    if (lane == 0) { slv[i] = lacc; cvec[i] = cacc; }

    const int by = i >> 7, r = i & 127;
    const int rsw = (r >> 1) & 3;
    char* const abase = (char*)Ab + (size_t)by * KB * TILE_BYTES + r * 64;
    char* const bbase = (char*)Bb + (size_t)by * KB * TILE_BYTES + r * 64;
    // store 4 bf16 (8B) at global k index k (k multiple of 4)
    #define ST4(base, k, v0, v1, v2, v3)                                           \
        {   const int kk = (k);                                                    \
            const int kb = kk >> 5, sl = ((kk >> 3) & 3) ^ rsw, hf = (kk >> 2) & 1;\
            ushort4 pk = {f2bf(v0), f2bf(v1), f2bf(v2), f2bf(v3)};                 \
            *(ushort4*)((base) + (size_t)kb * TILE_BYTES + sl * 16 + hf * 8) = pk; }
    ST4(abase, lane * 4,          mu.x * mu.x + va.x, mu.y * mu.y + va.y,
                                  mu.z * mu.z + va.z, mu.w * mu.w + va.w)
    ST4(abase, 256 + lane * 4,    -2.0f * mu.x, -2.0f * mu.y, -2.0f * mu.z, -2.0f * mu.w)
    ST4(bbase, lane * 4,          iv.x, iv.y, iv.z, iv.w)
    ST4(bbase, 256 + lane * 4,    mu.x * iv.x, mu.y * iv.y, mu.z * iv.z, mu.w * iv.w)
    #undef ST4
}

// ---------------------------------------------------------------------------
// Kernel 2: bf16 MFMA GEMM (128x128 tile, 4 waves 2x2, BK=32, K=512) with
// fused logsumexp epilogue (two-pass: max-reduce, then exp-sum-reduce).
// sim[i,j] = 5*dot(A_i,B_j) + colv[j] - 5*slv[i]; diagonal excluded.
// ---------------------------------------------------------------------------
__global__ __launch_bounds__(256) void gemm_lse_kernel(
        const unsigned short* __restrict__ Ab, const unsigned short* __restrict__ Bb,
        const float* __restrict__ slv, const float* __restrict__ cvec,
        float* __restrict__ pm, float* __restrict__ ps) {
    __shared__ __align__(16) char smem[16384];
    const int t = threadIdx.x;
    const int lane = t & 63, wid = t >> 6;
    const int bx = blockIdx.x, by = blockIdx.y;
    const int wrow = wid >> 1, wcol = wid & 1;
    const int fr = lane & 15, g = lane >> 4;

    // swizzled LDS read offsets (one 16B slot per fragment)
    int a_off[4], b_off[4];
    #pragma unroll
    for (int fm = 0; fm < 4; ++fm) {
        const int row = wrow * 64 + fm * 16 + fr;
        a_off[fm] = row * 64 + ((g ^ ((row >> 1) & 3)) << 4);
    }
    #pragma unroll
    for (int fn = 0; fn < 4; ++fn) {
        const int row = wcol * 64 + fn * 16 + fr;
        b_off[fn] = 8192 + row * 64 + ((g ^ ((row >> 1) & 3)) << 4);
    }

    f32x4 acc[4][4];
    #pragma unroll
    for (int i = 0; i < 4; ++i)
        #pragma unroll
        for (int j = 0; j < 4; ++j) acc[i][j] = (f32x4){0.f, 0.f, 0.f, 0.f};

    const char* gA = (const char*)Ab + (size_t)by * KB * TILE_BYTES;
    const char* gB = (const char*)Bb + (size_t)bx * KB * TILE_BYTES;

    for (int kk = 0; kk < KB; ++kk) {
        const char* tA = gA + kk * TILE_BYTES;
        const char* tB = gB + kk * TILE_BYTES;
        gll16(tA + wid * 1024 + lane * 16,        smem + wid * 1024);
        gll16(tA + 4096 + wid * 1024 + lane * 16, smem + 4096 + wid * 1024);
        gll16(tB + wid * 1024 + lane * 16,        smem + 8192 + wid * 1024);
        gll16(tB + 4096 + wid * 1024 + lane * 16, smem + 12288 + wid * 1024);
        __syncthreads();   // drains vmcnt -> tiles resident
        bf16x8 af[4], bfr[4];
        #pragma unroll
        for (int fm = 0; fm < 4; ++fm) af[fm] = *(const bf16x8*)(smem + a_off[fm]);
        #pragma unroll
        for (int fn = 0; fn < 4; ++fn) bfr[fn] = *(const bf16x8*)(smem + b_off[fn]);
        #pragma unroll
        for (int fm = 0; fm < 4; ++fm)
            #pragma unroll
            for (int fn = 0; fn < 4; ++fn)
                acc[fm][fn] = __builtin_amdgcn_mfma_f32_16x16x32_bf16(
                    af[fm], bfr[fn], acc[fm][fn], 0, 0, 0);
        __syncthreads();   // all reads done before next overwrite
    }

    // ---- fused LSE epilogue over this 128x128 sim block ----
    float colv[4]; int gcol[4];
    #pragma unroll
    for (int fn = 0; fn < 4; ++fn) {
        const int c = bx * 128 + wcol * 64 + fn * 16 + fr;
        gcol[fn] = c;
        colv[fn] = 5.0f * (slv[c] + cvec[c]) - 1280.0f;   // 5*(slv+cvec-256)
    }
    float* redm = (float*)smem;            // [128][2]
    float* reds = (float*)(smem + 1024);   // [128][2]

    #pragma unroll
    for (int fm = 0; fm < 4; ++fm) {
        #pragma unroll
        for (int q = 0; q < 4; ++q) {
            const int rloc = wrow * 64 + fm * 16 + g * 4 + q;
            const int grow = by * 128 + rloc;
            const float rv = 5.0f * slv[grow];
            float v[4];
            #pragma unroll
            for (int fn = 0; fn < 4; ++fn) {
                const float x = 5.0f * acc[fm][fn][q] + colv[fn] - rv;
                v[fn] = (grow == gcol[fn]) ? -3.0e38f : x;
            }
            // pass 1: max over 4 regs + 16 fr-lanes
            float m = fmaxf(fmaxf(v[0], v[1]), fmaxf(v[2], v[3]));
            #pragma unroll
            for (int off = 1; off < 16; off <<= 1) m = fmaxf(m, __shfl_xor(m, off, 64));
            // pass 2: exp-sum over 4 regs + 16 fr-lanes
            float s = __expf(v[0] - m) + __expf(v[1] - m) + __expf(v[2] - m) + __expf(v[3] - m);
            #pragma unroll
            for (int off = 1; off < 16; off <<= 1) s += __shfl_xor(s, off, 64);
            if (fr == 0) { redm[rloc * 2 + wcol] = m; reds[rloc * 2 + wcol] = s; }
        }
    }
    __syncthreads();
    if (t < 128) {
        const float m0 = redm[t * 2], m1 = redm[t * 2 + 1];
        const float s0 = reds[t * 2], s1v = reds[t * 2 + 1];
        const float m = fmaxf(m0, m1);
        const float s = s0 * __expf(m0 - m) + s1v * __expf(m1 - m);
        pm[(size_t)(by * 128 + t) * NBLK + bx] = m;
        ps[(size_t)(by * 128 + t) * NBLK + bx] = s;
    }
}

// ---------------------------------------------------------------------------
// Kernel 3: per-row finalize. Combine 32 (m,s) partials -> lse; exact fp32
// pos term from raw inputs; loss[i] = lse - sim_pos.
// d already includes the c_j term — do NOT add cvec[j].
// ---------------------------------------------------------------------------
__global__ __launch_bounds__(256) void finalize_kernel(
        const float* __restrict__ loc1, const float* __restrict__ scale1,
        const float* __restrict__ loc2, const float* __restrict__ scale2,
        const float* __restrict__ slv,
        const float* __restrict__ pm, const float* __restrict__ ps,
        float* __restrict__ loss) {
    const int t = threadIdx.x, w = t >> 6, lane = t & 63;
    const int i = blockIdx.x * 4 + w;
    const int j = (i < N_HALF) ? i + N_HALF : i - N_HALF;
    const float* mui_p  = (i < N_HALF) ? loc1 + (size_t)i * D_DIM   : loc2 + (size_t)(i - N_HALF) * D_DIM;
    const float* vari_p = (i < N_HALF) ? scale1 + (size_t)i * D_DIM : scale2 + (size_t)(i - N_HALF) * D_DIM;
    const float* muj_p  = (j < N_HALF) ? loc1 + (size_t)j * D_DIM   : loc2 + (size_t)(j - N_HALF) * D_DIM;
    const float* varj_p = (j < N_HALF) ? scale1 + (size_t)j * D_DIM : scale2 + (size_t)(j - N_HALF) * D_DIM;

    const float4 mi = *(const float4*)(mui_p  + lane * 4);
    const float4 vi = *(const float4*)(vari_p + lane * 4);
    const float4 mj = *(const float4*)(muj_p  + lane * 4);
    const float4 vj = *(const float4*)(varj_p + lane * 4);
    float d = 0.0f;
    { float dx = mi.x - mj.x; d += (dx * dx + vi.x) / vj.x; }
    { float dx = mi.y - mj.y; d += (dx * dx + vi.y) / vj.y; }
    { float dx = mi.z - mj.z; d += (dx * dx + vi.z) / vj.z; }
    { float dx = mi.w - mj.w; d += (dx * dx + vi.w) / vj.w; }
    #pragma unroll
    for (int off = 1; off < 64; off <<= 1) d += __shfl_xor(d, off, 64);

    float m = (lane < NBLK) ? pm[(size_t)i * NBLK + lane] : -3.0e38f;
    float s = (lane < NBLK) ? ps[(size_t)i * NBLK + lane] : 0.0f;
    #pragma unroll
    for (int off = 1; off < NBLK; off <<= 1) {
        const float om = __shfl_xor(m, off, 64);
        const float os = __shfl_xor(s, off, 64);
        const float nm = fmaxf(m, om);
        s = s * __expf(m - nm) + os * __expf(om - nm);
        m = nm;
    }
    if (lane == 0) {
        const float lse = m + logf(s);
        const float simpos = 5.0f * (slv[j] - slv[i] - 256.0f + d);
        loss[i] = lse - simpos;
    }
}

// ---------------------------------------------------------------------------
// Kernel 4: mean over M rows -> d_out[0]
// ---------------------------------------------------------------------------
__global__ __launch_bounds__(256) void mean_kernel(const float* __restrict__ loss,
                                                   float* __restrict__ out) {
    __shared__ float sm[256];
    const int t = threadIdx.x;
    float acc = 0.0f;
    for (int k = t; k < M_TOT; k += 256) acc += loss[k];
    sm[t] = acc;
    __syncthreads();
    for (int off = 128; off > 0; off >>= 1) {
        if (t < off) sm[t] += sm[t + off];
        __syncthreads();
    }
    if (t == 0) out[0] = sm[0] * (1.0f / (float)M_TOT);
}

// ---------------------------------------------------------------------------
extern "C" void kernel_launch(void* const* d_in, const int* in_sizes, int n_in,
                              void* d_out, int out_size, void* d_ws, size_t ws_size,
                              hipStream_t stream) {
    const float* loc1   = (const float*)d_in[0];
    const float* scale1 = (const float*)d_in[1];
    const float* loc2   = (const float*)d_in[2];
    const float* scale2 = (const float*)d_in[3];
    float* out = (float*)d_out;

    char* ws = (char*)d_ws;
    unsigned short* Ab = (unsigned short*)ws;                              // 4 MB
    unsigned short* Bb = (unsigned short*)(ws + (size_t)4 * 1024 * 1024);  // 4 MB
    float* slv  = (float*)(ws + (size_t)8 * 1024 * 1024);                  // 16 KB
    float* cvec = slv + M_TOT;
    float* pm   = cvec + M_TOT;                                            // 512 KB
    float* ps   = pm + (size_t)M_TOT * NBLK;                               // 512 KB
    float* loss = ps + (size_t)M_TOT * NBLK;                               // 16 KB

    hipLaunchKernelGGL(prep_kernel, dim3(M_TOT / 4), dim3(256), 0, stream,
                       loc1, scale1, loc2, scale2, Ab, Bb, slv, cvec);
    hipLaunchKernelGGL(gemm_lse_kernel, dim3(NBLK, NBLK), dim3(256), 0, stream,
                       Ab, Bb, slv, cvec, pm, ps);
    hipLaunchKernelGGL(finalize_kernel, dim3(M_TOT / 4), dim3(256), 0, stream,
                       loc1, scale1, loc2, scale2, slv, pm, ps, loss);
    hipLaunchKernelGGL(mean_kernel, dim3(1), dim3(256), 0, stream, loss, out);
}

// Round 5
// 49.394 us; speedup vs baseline: 1.1395x; 1.1395x over previous
//
#include <hip/hip_runtime.h>
#include <hip/hip_bf16.h>
#include <math.h>

#define N_HALF 2048
#define M_TOT  4096
#define D_DIM  256
#define K2     512
#define NBLK   16            // M_TOT / 256 column blocks
#define NKT    8             // K2 / 64 k-tiles
#define TILE_BYTES 32768     // 256 rows * 64 k * 2 B

typedef __attribute__((ext_vector_type(8))) short bf16x8;
typedef __attribute__((ext_vector_type(4))) float f32x4;

static __device__ __forceinline__ unsigned short f2bf(float x) {
    union { __hip_bfloat16 h; unsigned short u; } cv;
    cv.h = __float2bfloat16(x);
    return cv.u;
}

static __device__ __forceinline__ void gll16(const void* g, void* l) {
    __builtin_amdgcn_global_load_lds(
        (const __attribute__((address_space(1))) unsigned int*)g,
        (__attribute__((address_space(3))) unsigned int*)l, 16, 0, 0);
}

// ---------------------------------------------------------------------------
// Kernel 1: build bf16 GEMM operands (pre-swizzled, tile-major) + row scalars.
//   A[i] = [mu^2+var , -2*mu],  B[j] = [1/var , mu/var]   (each K=512)
//   Global layout: tiles (rowblk 0..15, ktile 0..7) of 256 rows x 64 k bf16
//   (32 KB). Within a tile, row r's 8 16B-slots are XOR-swizzled:
//   slot' = slot ^ (r&7). A linear global_load_lds copy then yields the
//   swizzled LDS image directly (swizzle both sides: source + read).
// ---------------------------------------------------------------------------
__global__ __launch_bounds__(256) void prep_kernel(
        const float* __restrict__ loc1, const float* __restrict__ scale1,
        const float* __restrict__ loc2, const float* __restrict__ scale2,
        unsigned short* __restrict__ Ab, unsigned short* __restrict__ Bb,
        float* __restrict__ slv, float* __restrict__ cvec) {
    const int t = threadIdx.x, w = t >> 6, lane = t & 63;
    const int i = blockIdx.x * 4 + w;
    const float* mup  = (i < N_HALF) ? loc1 + (size_t)i * D_DIM   : loc2 + (size_t)(i - N_HALF) * D_DIM;
    const float* vap  = (i < N_HALF) ? scale1 + (size_t)i * D_DIM : scale2 + (size_t)(i - N_HALF) * D_DIM;
    const float4 mu = *(const float4*)(mup + lane * 4);
    const float4 va = *(const float4*)(vap + lane * 4);
    const float4 iv = {1.0f / va.x, 1.0f / va.y, 1.0f / va.z, 1.0f / va.w};

    float lacc = __logf(va.x * va.y * va.z * va.w);
    float cacc = mu.x * mu.x * iv.x + mu.y * mu.y * iv.y
               + mu.z * mu.z * iv.z + mu.w * mu.w * iv.w;
    #pragma unroll
    for (int off = 1; off < 64; off <<= 1) {
        lacc += __shfl_xor(lacc, off, 64);
        cacc += __shfl_xor(cacc, off, 64);
    }
    if (lane == 0) { slv[i] = lacc; cvec[i] = cacc; }

    const int by = i >> 8, r = i & 255;
    const int rsw = r & 7;
    char* const abase = (char*)Ab + (size_t)by * (NKT * TILE_BYTES) + r * 128;
    char* const bbase = (char*)Bb + (size_t)by * (NKT * TILE_BYTES) + r * 128;
    // store 4 bf16 (8B) at global k index kk (multiple of 4)
    #define ST4(base, k, v0, v1, v2, v3)                                            \
        {   const int kk = (k);                                                     \
            const int kb = kk >> 6, sl = ((kk >> 3) & 7) ^ rsw, hf = (kk >> 2) & 1; \
            ushort4 pk = {f2bf(v0), f2bf(v1), f2bf(v2), f2bf(v3)};                  \
            *(ushort4*)((base) + (size_t)kb * TILE_BYTES + sl * 16 + hf * 8) = pk; }
    ST4(abase, lane * 4,          mu.x * mu.x + va.x, mu.y * mu.y + va.y,
                                  mu.z * mu.z + va.z, mu.w * mu.w + va.w)
    ST4(abase, 256 + lane * 4,    -2.0f * mu.x, -2.0f * mu.y, -2.0f * mu.z, -2.0f * mu.w)
    ST4(bbase, lane * 4,          iv.x, iv.y, iv.z, iv.w)
    ST4(bbase, 256 + lane * 4,    mu.x * iv.x, mu.y * iv.y, mu.z * iv.z, mu.w * iv.w)
    #undef ST4
}

// ---------------------------------------------------------------------------
// Kernel 2: bf16 MFMA GEMM, 256x256 tile, 8 waves (2Mx4N, wave tile 128x64),
// BK=64, double-buffered LDS (128 KB), counted-vmcnt 2-K-tile pipeline:
// compute(buf cur) | barrier | STAGE(cur <- kt+2) | vmcnt(8) | barrier.
// Loads stay in flight across barriers (never vmcnt(0) in steady state).
// Fused logsumexp epilogue writes (m,s) per (row, colblock).
// ---------------------------------------------------------------------------
__global__ __launch_bounds__(512, 2) void gemm_lse_kernel(
        const unsigned short* __restrict__ Ab, const unsigned short* __restrict__ Bb,
        const float* __restrict__ slv, const float* __restrict__ cvec,
        float* __restrict__ pm, float* __restrict__ ps) {
    extern __shared__ __align__(16) char smem[];   // 131072 B: 2 bufs x (A 32K + B 32K)
    const int t = threadIdx.x;
    const int lane = t & 63, wid = t >> 6;
    const int bx = blockIdx.x, by = blockIdx.y;
    const int wrow = wid >> 2, wcol = wid & 3;     // 2 x 4 wave grid
    const int fr = lane & 15, g = lane >> 4;
    const int t16 = t * 16;

    // swizzled LDS read offsets: row*128 + ((slot ^ (row&7))<<4), slot = ks*4+g
    int a_off[8][2], b_off[4][2];
    #pragma unroll
    for (int fm = 0; fm < 8; ++fm) {
        const int row = wrow * 128 + fm * 16 + fr;
        #pragma unroll
        for (int ks = 0; ks < 2; ++ks)
            a_off[fm][ks] = row * 128 + ((((ks * 4 + g) ^ (row & 7))) << 4);
    }
    #pragma unroll
    for (int fn = 0; fn < 4; ++fn) {
        const int row = wcol * 64 + fn * 16 + fr;
        #pragma unroll
        for (int ks = 0; ks < 2; ++ks)
            b_off[fn][ks] = 32768 + row * 128 + ((((ks * 4 + g) ^ (row & 7))) << 4);
    }

    f32x4 acc[8][4];
    #pragma unroll
    for (int i = 0; i < 8; ++i)
        #pragma unroll
        for (int j = 0; j < 4; ++j) acc[i][j] = (f32x4){0.f, 0.f, 0.f, 0.f};

    const char* gA = (const char*)Ab + (size_t)by * (NKT * TILE_BYTES);
    const char* gB = (const char*)Bb + (size_t)bx * (NKT * TILE_BYTES);

    // stage one K-tile (A 32K + B 32K) into buffer `buf`: 8 gll16 per thread
    #define STAGE(buf, kt)                                                       \
        {   const char* _tA = gA + (size_t)(kt) * TILE_BYTES;                    \
            const char* _tB = gB + (size_t)(kt) * TILE_BYTES;                    \
            char* _dA = smem + (buf) * 65536;                                    \
            char* _dB = _dA + 32768;                                             \
            gll16(_tA + t16,         _dA + t16);                                 \
            gll16(_tA + 8192 + t16,  _dA + 8192 + t16);                          \
            gll16(_tA + 16384 + t16, _dA + 16384 + t16);                         \
            gll16(_tA + 24576 + t16, _dA + 24576 + t16);                         \
            gll16(_tB + t16,         _dB + t16);                                 \
            gll16(_tB + 8192 + t16,  _dB + 8192 + t16);                          \
            gll16(_tB + 16384 + t16, _dB + 16384 + t16);                         \
            gll16(_tB + 24576 + t16, _dB + 24576 + t16); }

    STAGE(0, 0)
    STAGE(1, 1)
    asm volatile("s_waitcnt vmcnt(8)" ::: "memory");   // tile 0 resident (tile 1 in flight)
    __builtin_amdgcn_s_barrier();
    asm volatile("" ::: "memory");

    for (int kt = 0; kt < NKT; ++kt) {
        const char* bT = smem + (kt & 1) * 65536;
        #pragma unroll
        for (int ks = 0; ks < 2; ++ks) {
            bf16x8 b0 = *(const bf16x8*)(bT + b_off[0][ks]);
            bf16x8 b1 = *(const bf16x8*)(bT + b_off[1][ks]);
            bf16x8 b2 = *(const bf16x8*)(bT + b_off[2][ks]);
            bf16x8 b3 = *(const bf16x8*)(bT + b_off[3][ks]);
            #pragma unroll
            for (int fm = 0; fm < 8; ++fm) {
                const bf16x8 af = *(const bf16x8*)(bT + a_off[fm][ks]);
                acc[fm][0] = __builtin_amdgcn_mfma_f32_16x16x32_bf16(af, b0, acc[fm][0], 0, 0, 0);
                acc[fm][1] = __builtin_amdgcn_mfma_f32_16x16x32_bf16(af, b1, acc[fm][1], 0, 0, 0);
                acc[fm][2] = __builtin_amdgcn_mfma_f32_16x16x32_bf16(af, b2, acc[fm][2], 0, 0, 0);
                acc[fm][3] = __builtin_amdgcn_mfma_f32_16x16x32_bf16(af, b3, acc[fm][3], 0, 0, 0);
            }
        }
        asm volatile("" ::: "memory");
        __builtin_amdgcn_s_barrier();                  // all waves done reading buf
        asm volatile("" ::: "memory");
        if (kt + 2 < NKT) {
            STAGE(kt & 1, kt + 2)                      // overwrite; overlaps next compute
            asm volatile("s_waitcnt vmcnt(8)" ::: "memory");   // tile kt+1 resident
            __builtin_amdgcn_s_barrier();
            asm volatile("" ::: "memory");
        } else if (kt < NKT - 1) {
            asm volatile("s_waitcnt vmcnt(0)" ::: "memory");   // last tile resident
            __builtin_amdgcn_s_barrier();
            asm volatile("" ::: "memory");
        }
    }
    #undef STAGE

    // ---- fused LSE epilogue over this 256x256 sim block ----
    float colv[4]; int gcol[4];
    #pragma unroll
    for (int fn = 0; fn < 4; ++fn) {
        const int c = bx * 256 + wcol * 64 + fn * 16 + fr;
        gcol[fn] = c;
        colv[fn] = 5.0f * (slv[c] + cvec[c]) - 1280.0f;   // 5*(slv+cvec-256)
    }
    float* redm = (float*)smem;             // [256][4]
    float* reds = (float*)(smem + 4096);    // [256][4]

    #pragma unroll
    for (int fm = 0; fm < 8; ++fm) {
        #pragma unroll
        for (int q = 0; q < 4; ++q) {
            const int rloc = wrow * 128 + fm * 16 + g * 4 + q;
            const int grow = by * 256 + rloc;
            const float rv = 5.0f * slv[grow];
            float v[4];
            #pragma unroll
            for (int fn = 0; fn < 4; ++fn) {
                const float x = 5.0f * acc[fm][fn][q] + colv[fn] - rv;
                v[fn] = (grow == gcol[fn]) ? -3.0e38f : x;
            }
            float m = fmaxf(fmaxf(v[0], v[1]), fmaxf(v[2], v[3]));
            #pragma unroll
            for (int off = 1; off < 16; off <<= 1) m = fmaxf(m, __shfl_xor(m, off, 64));
            float s = __expf(v[0] - m) + __expf(v[1] - m) + __expf(v[2] - m) + __expf(v[3] - m);
            #pragma unroll
            for (int off = 1; off < 16; off <<= 1) s += __shfl_xor(s, off, 64);
            if (fr == 0) { redm[rloc * 4 + wcol] = m; reds[rloc * 4 + wcol] = s; }
        }
    }
    __syncthreads();
    if (t < 256) {
        float m = redm[t * 4], s = reds[t * 4];
        #pragma unroll
        for (int k = 1; k < 4; ++k) {
            const float mk = redm[t * 4 + k], sk = reds[t * 4 + k];
            const float nm = fmaxf(m, mk);
            s = s * __expf(m - nm) + sk * __expf(mk - nm);
            m = nm;
        }
        pm[(size_t)(by * 256 + t) * NBLK + bx] = m;
        ps[(size_t)(by * 256 + t) * NBLK + bx] = s;
    }
}

// ---------------------------------------------------------------------------
// Kernel 3: per-row finalize. Combine 16 (m,s) partials -> lse; exact fp32
// pos term from raw inputs; loss[i] = lse - sim_pos.
// d already includes the c_j term — do NOT add cvec[j].
// ---------------------------------------------------------------------------
__global__ __launch_bounds__(256) void finalize_kernel(
        const float* __restrict__ loc1, const float* __restrict__ scale1,
        const float* __restrict__ loc2, const float* __restrict__ scale2,
        const float* __restrict__ slv,
        const float* __restrict__ pm, const float* __restrict__ ps,
        float* __restrict__ loss) {
    const int t = threadIdx.x, w = t >> 6, lane = t & 63;
    const int i = blockIdx.x * 4 + w;
    const int j = (i < N_HALF) ? i + N_HALF : i - N_HALF;
    const float* mui_p  = (i < N_HALF) ? loc1 + (size_t)i * D_DIM   : loc2 + (size_t)(i - N_HALF) * D_DIM;
    const float* vari_p = (i < N_HALF) ? scale1 + (size_t)i * D_DIM : scale2 + (size_t)(i - N_HALF) * D_DIM;
    const float* muj_p  = (j < N_HALF) ? loc1 + (size_t)j * D_DIM   : loc2 + (size_t)(j - N_HALF) * D_DIM;
    const float* varj_p = (j < N_HALF) ? scale1 + (size_t)j * D_DIM : scale2 + (size_t)(j - N_HALF) * D_DIM;

    const float4 mi = *(const float4*)(mui_p  + lane * 4);
    const float4 vi = *(const float4*)(vari_p + lane * 4);
    const float4 mj = *(const float4*)(muj_p  + lane * 4);
    const float4 vj = *(const float4*)(varj_p + lane * 4);
    float d = 0.0f;
    { float dx = mi.x - mj.x; d += (dx * dx + vi.x) / vj.x; }
    { float dx = mi.y - mj.y; d += (dx * dx + vi.y) / vj.y; }
    { float dx = mi.z - mj.z; d += (dx * dx + vi.z) / vj.z; }
    { float dx = mi.w - mj.w; d += (dx * dx + vi.w) / vj.w; }
    #pragma unroll
    for (int off = 1; off < 64; off <<= 1) d += __shfl_xor(d, off, 64);

    float m = (lane < NBLK) ? pm[(size_t)i * NBLK + lane] : -3.0e38f;
    float s = (lane < NBLK) ? ps[(size_t)i * NBLK + lane] : 0.0f;
    #pragma unroll
    for (int off = 1; off < NBLK; off <<= 1) {
        const float om = __shfl_xor(m, off, 64);
        const float os = __shfl_xor(s, off, 64);
        const float nm = fmaxf(m, om);
        s = s * __expf(m - nm) + os * __expf(om - nm);
        m = nm;
    }
    if (lane == 0) {
        const float lse = m + logf(s);
        const float simpos = 5.0f * (slv[j] - slv[i] - 256.0f + d);
        loss[i] = lse - simpos;
    }
}

// ---------------------------------------------------------------------------
// Kernel 4: mean over M rows -> d_out[0]
// ---------------------------------------------------------------------------
__global__ __launch_bounds__(256) void mean_kernel(const float* __restrict__ loss,
                                                   float* __restrict__ out) {
    __shared__ float sm[256];
    const int t = threadIdx.x;
    float acc = 0.0f;
    for (int k = t; k < M_TOT; k += 256) acc += loss[k];
    sm[t] = acc;
    __syncthreads();
    for (int off = 128; off > 0; off >>= 1) {
        if (t < off) sm[t] += sm[t + off];
        __syncthreads();
    }
    if (t == 0) out[0] = sm[0] * (1.0f / (float)M_TOT);
}

// ---------------------------------------------------------------------------
extern "C" void kernel_launch(void* const* d_in, const int* in_sizes, int n_in,
                              void* d_out, int out_size, void* d_ws, size_t ws_size,
                              hipStream_t stream) {
    const float* loc1   = (const float*)d_in[0];
    const float* scale1 = (const float*)d_in[1];
    const float* loc2   = (const float*)d_in[2];
    const float* scale2 = (const float*)d_in[3];
    float* out = (float*)d_out;

    char* ws = (char*)d_ws;
    unsigned short* Ab = (unsigned short*)ws;                              // 4 MB
    unsigned short* Bb = (unsigned short*)(ws + (size_t)4 * 1024 * 1024);  // 4 MB
    float* slv  = (float*)(ws + (size_t)8 * 1024 * 1024);                  // 16 KB
    float* cvec = slv + M_TOT;
    float* pm   = cvec + M_TOT;                                            // 256 KB
    float* ps   = pm + (size_t)M_TOT * NBLK;                               // 256 KB
    float* loss = ps + (size_t)M_TOT * NBLK;                               // 16 KB

    hipLaunchKernelGGL(prep_kernel, dim3(M_TOT / 4), dim3(256), 0, stream,
                       loc1, scale1, loc2, scale2, Ab, Bb, slv, cvec);
    hipLaunchKernelGGL(gemm_lse_kernel, dim3(NBLK, NBLK), dim3(512), 131072, stream,
                       Ab, Bb, slv, cvec, pm, ps);
    hipLaunchKernelGGL(finalize_kernel, dim3(M_TOT / 4), dim3(256), 0, stream,
                       loc1, scale1, loc2, scale2, slv, pm, ps, loss);
    hipLaunchKernelGGL(mean_kernel, dim3(1), dim3(256), 0, stream, loss, out);
}